// Round 1
// baseline (248.509 us; speedup 1.0000x reference)
//
#include <hip/hip_runtime.h>
#include <hip/hip_bf16.h>
#include <math.h>

#define NN 8192
#define ALPHAF 0.1f

typedef __attribute__((ext_vector_type(8))) short short8;
typedef __attribute__((ext_vector_type(16))) float f32x16;

union U8 { unsigned u[4]; short8 v; };

__device__ inline unsigned short f2bf(float x) {
  union { float f; unsigned u; } t; t.f = x;
  unsigned r = t.u + 0x7fffu + ((t.u >> 16) & 1u);
  return (unsigned short)(r >> 16);
}
__device__ inline unsigned pack2(float lo, float hi) {
  return (unsigned)f2bf(lo) | ((unsigned)f2bf(hi) << 16);
}

// ---------------------------------------------------------------------------
// Kernel 1: Q = LN(X@Qw^T+Qb), K = LN(H@Kw^T+Kb), V = BN(H@Vw^T+Vb)
// writes Qbf, Kbf row-major bf16; VT, HT transposed bf16 [64][8192].
// One wave per 4 rows; weights held in 64 VGPRs per phase.
// ---------------------------------------------------------------------------
__global__ __launch_bounds__(256) void qkv_kernel(
    const float* __restrict__ X, const float* __restrict__ H,
    const float* __restrict__ Qw, const float* __restrict__ Qb,
    const float* __restrict__ Kw, const float* __restrict__ Kb,
    const float* __restrict__ Vw, const float* __restrict__ Vb,
    const float* __restrict__ bng, const float* __restrict__ bnb,
    const float* __restrict__ bnm, const float* __restrict__ bnv,
    unsigned short* __restrict__ Qbf, unsigned short* __restrict__ Kbf,
    unsigned short* __restrict__ VT, unsigned short* __restrict__ HT)
{
  int wid = (blockIdx.x * blockDim.x + threadIdx.x) >> 6; // 0..2047
  int d = threadIdx.x & 63;
  float4 w[16];

  // ---- Q phase (from X)
  for (int fq = 0; fq < 16; fq++) w[fq] = *(const float4*)(Qw + d*64 + fq*4);
  for (int rr = 0; rr < 4; rr++) {
    int r = wid*4 + rr;
    float a = Qb[d];
    for (int fq = 0; fq < 16; fq++) {
      float4 xv = *(const float4*)(X + r*64 + fq*4);
      a += w[fq].x*xv.x + w[fq].y*xv.y + w[fq].z*xv.z + w[fq].w*xv.w;
    }
    float s = a;
    for (int off = 32; off; off >>= 1) s += __shfl_xor(s, off);
    float mean = s * (1.f/64.f);
    float c = a - mean;
    float s2 = c*c;
    for (int off = 32; off; off >>= 1) s2 += __shfl_xor(s2, off);
    float q = c * rsqrtf(s2*(1.f/64.f) + 1e-5f);
    Qbf[r*64 + d] = f2bf(q);
  }
  // ---- K phase (from H)
  for (int fq = 0; fq < 16; fq++) w[fq] = *(const float4*)(Kw + d*64 + fq*4);
  for (int rr = 0; rr < 4; rr++) {
    int r = wid*4 + rr;
    float a = Kb[d];
    for (int fq = 0; fq < 16; fq++) {
      float4 hv = *(const float4*)(H + r*64 + fq*4);
      a += w[fq].x*hv.x + w[fq].y*hv.y + w[fq].z*hv.z + w[fq].w*hv.w;
    }
    float s = a;
    for (int off = 32; off; off >>= 1) s += __shfl_xor(s, off);
    float mean = s * (1.f/64.f);
    float c = a - mean;
    float s2 = c*c;
    for (int off = 32; off; off >>= 1) s2 += __shfl_xor(s2, off);
    float k = c * rsqrtf(s2*(1.f/64.f) + 1e-5f);
    Kbf[r*64 + d] = f2bf(k);
  }
  // ---- V phase (from H) + HT transpose
  for (int fq = 0; fq < 16; fq++) w[fq] = *(const float4*)(Vw + d*64 + fq*4);
  float bscale = rsqrtf(bnv[d] + 1e-5f) * bng[d];
  for (int rr = 0; rr < 4; rr++) {
    int r = wid*4 + rr;
    float a = Vb[d];
    for (int fq = 0; fq < 16; fq++) {
      float4 hv = *(const float4*)(H + r*64 + fq*4);
      a += w[fq].x*hv.x + w[fq].y*hv.y + w[fq].z*hv.z + w[fq].w*hv.w;
    }
    float v = (a - bnm[d]) * bscale + bnb[d];
    VT[(size_t)d*NN + r] = f2bf(v);
    HT[(size_t)d*NN + r] = f2bf(H[r*64 + d]);
  }
}

// ---------------------------------------------------------------------------
// Kernel 2: pass 1 — per-column (axis 0) online max / sum-exp partials.
// Non-swapped GEMM: D = Q(A) x K^T(B); lane <-> column j so M reads are
// fully coalesced 128B row segments straight from global (no LDS).
// Wave job: j-block (32 cols) x i-slice (512 rows).
// ---------------------------------------------------------------------------
__global__ __launch_bounds__(256) void pass1_kernel(
    const float* __restrict__ M, const unsigned short* __restrict__ Qbf,
    const unsigned short* __restrict__ Kbf,
    float* __restrict__ pm, float* __restrict__ pd)
{
  int wj = (blockIdx.x * blockDim.x + threadIdx.x) >> 6;  // 0..4095
  int lane = threadIdx.x & 63;
  int l31 = lane & 31, h = lane >> 5;
  int jb = wj & 255, slice = wj >> 8;
  int j = jb*32 + l31;

  short8 kb[4];
  for (int m = 0; m < 4; m++)
    kb[m] = *(const short8*)(Kbf + (size_t)j*64 + 16*m + 8*h);

  float mrun = -1e30f, drun = 0.f;
  for (int t = 0; t < 16; t++) {
    int i0 = (slice*16 + t) * 32;
    f32x16 acc;
    for (int r = 0; r < 16; r++) acc[r] = 0.f;
    for (int m = 0; m < 4; m++) {
      short8 qa = *(const short8*)(Qbf + (size_t)(i0 + l31)*64 + 16*m + 8*h);
      acc = __builtin_amdgcn_mfma_f32_32x32x16_bf16(qa, kb[m], acc, 0, 0, 0);
    }
    float sv[16]; float vmax = -1e30f;
    for (int r = 0; r < 16; r++) {
      int ir = (r&3) + 8*(r>>2) + 4*h;
      float Mv = M[(size_t)(i0 + ir)*NN + j];
      sv[r] = acc[r] * 0.125f * Mv;
      vmax = fmaxf(vmax, sv[r]);
    }
    float mn = fmaxf(mrun, vmax);
    float add = 0.f;
    for (int r = 0; r < 16; r++) add += __expf(sv[r] - mn);
    drun = drun * __expf(mrun - mn) + add;
    mrun = mn;
  }
  float m2 = __shfl_xor(mrun, 32), d2 = __shfl_xor(drun, 32);
  float mf = fmaxf(mrun, m2);
  float df = drun*__expf(mrun - mf) + d2*__expf(m2 - mf);
  if (lane < 32) {
    pm[(size_t)slice*NN + j] = mf;
    pd[(size_t)slice*NN + j] = df;
  }
}

// ---------------------------------------------------------------------------
// Kernel 3: combine 16 partial (m,d) per column -> colmax, colscale = alpha/D
// ---------------------------------------------------------------------------
__global__ __launch_bounds__(256) void combine_kernel(
    const float* __restrict__ pm, const float* __restrict__ pd,
    float* __restrict__ colmax, float* __restrict__ colscale)
{
  int j = blockIdx.x * blockDim.x + threadIdx.x;
  float m = -1e30f;
  for (int s = 0; s < 16; s++) m = fmaxf(m, pm[(size_t)s*NN + j]);
  float Dv = 0.f;
  for (int s = 0; s < 16; s++) Dv += pd[(size_t)s*NN + j] * __expf(pm[(size_t)s*NN + j] - m);
  colmax[j] = m;
  colscale[j] = ALPHAF / Dv;
}

// ---------------------------------------------------------------------------
// Kernel 4: pass 2 — out = alpha*A@V + M@H.
// Swapped GEMM s^T = K(A) x Q^T(B) so lane <-> output row i; P fragments
// built in-register via cvt_pk + shfl_xor(32) half-swap; M@H fused using the
// same LDS-staged M tile (stride-33 pad, double-buffered).
// Grid: 64 i-blocks (128 rows) x 8 j-slices (1024 cols); 8 waves/WG:
// wave = (i-quarter, d-half). atomicAdd epilogue.
// ---------------------------------------------------------------------------
__global__ __launch_bounds__(512) void pass2_kernel(
    const float* __restrict__ M, const unsigned short* __restrict__ Qbf,
    const unsigned short* __restrict__ Kbf, const unsigned short* __restrict__ VT,
    const unsigned short* __restrict__ HT, const float* __restrict__ colmax,
    const float* __restrict__ colscale, float* __restrict__ out)
{
  __shared__ float mt[2][128*33];
  int iblk = blockIdx.x >> 3, slice = blockIdx.x & 7;
  int i0 = iblk * 128;
  int tid = threadIdx.x;
  int lane = tid & 63, wid = tid >> 6;
  int l31 = lane & 31, h = lane >> 5;
  int iq = wid & 3, dh = wid >> 2;

  // Q B-frags: fixed for the whole WG lifetime (16 VGPRs)
  short8 qb[4];
  {
    int irow = i0 + iq*32 + l31;
    for (int m = 0; m < 4; m++)
      qb[m] = *(const short8*)(Qbf + (size_t)irow*64 + 16*m + 8*h);
  }
  f32x16 oacc;
  for (int r = 0; r < 16; r++) oacc[r] = 0.f;

  // staging assignment: thread -> (row, 8-float column group)
  int srow = tid >> 2, scg = (tid & 3) * 8;
  const float* Msrc = M + (size_t)(i0 + srow)*NN + slice*1024 + scg;
  float* lw0 = &mt[0][srow*33 + scg];
  float* lw1 = &mt[1][srow*33 + scg];

  float4 ra = *(const float4*)(Msrc);
  float4 rb = *(const float4*)(Msrc + 4);
  { float* w = lw0;
    w[0]=ra.x; w[1]=ra.y; w[2]=ra.z; w[3]=ra.w;
    w[4]=rb.x; w[5]=rb.y; w[6]=rb.z; w[7]=rb.w; }
  __syncthreads();

  for (int t = 0; t < 32; t++) {
    int jt = slice*1024 + t*32;
    if (t+1 < 32) {
      ra = *(const float4*)(Msrc + (t+1)*32);
      rb = *(const float4*)(Msrc + (t+1)*32 + 4);
    }
    const float* lb = mt[t & 1];

    // s^T = K x Q^T  (D: col = i = l31, row = j = jr)
    f32x16 sacc;
    for (int r = 0; r < 16; r++) sacc[r] = 0.f;
    for (int m = 0; m < 4; m++) {
      short8 ka = *(const short8*)(Kbf + (size_t)(jt + l31)*64 + 16*m + 8*h);
      sacc = __builtin_amdgcn_mfma_f32_32x32x16_bf16(ka, qb[m], sacc, 0, 0, 0);
    }

    float cmv = colmax[jt + l31];
    float csv = colscale[jt + l31];
    float p[16], mb[16];
    for (int r = 0; r < 16; r++) {
      int jr = (r&3) + 8*(r>>2) + 4*h;
      float Mv = lb[(iq*32 + l31)*33 + jr];
      float s = sacc[r] * 0.125f * Mv;
      float cm = __shfl(cmv, jr);
      float cs = __shfl(csv, jr);
      p[r] = __expf(s - cm) * cs;   // alpha folded into colscale
      mb[r] = Mv;
    }
    unsigned pu[8], mu[8], ps[8], ms[8];
    for (int q = 0; q < 4; q++) {
      pu[2*q]   = pack2(p[4*q],    p[4*q+1]);
      pu[2*q+1] = pack2(p[4*q+2],  p[4*q+3]);
      mu[2*q]   = pack2(mb[4*q],   mb[4*q+1]);
      mu[2*q+1] = pack2(mb[4*q+2], mb[4*q+3]);
    }
    for (int k = 0; k < 8; k++) {
      ps[k] = __shfl_xor(pu[k], 32);
      ms[k] = __shfl_xor(mu[k], 32);
    }
    U8 A1, A2, Am1, Am2;
    A1.u[0] = h ? ps[2] : pu[0];  A1.u[1] = h ? ps[3] : pu[1];
    A1.u[2] = h ? pu[2] : ps[0];  A1.u[3] = h ? pu[3] : ps[1];
    A2.u[0] = h ? ps[6] : pu[4];  A2.u[1] = h ? ps[7] : pu[5];
    A2.u[2] = h ? pu[6] : ps[4];  A2.u[3] = h ? pu[7] : ps[5];
    Am1.u[0] = h ? ms[2] : mu[0]; Am1.u[1] = h ? ms[3] : mu[1];
    Am1.u[2] = h ? mu[2] : ms[0]; Am1.u[3] = h ? mu[3] : ms[1];
    Am2.u[0] = h ? ms[6] : mu[4]; Am2.u[1] = h ? ms[7] : mu[5];
    Am2.u[2] = h ? mu[6] : ms[4]; Am2.u[3] = h ? mu[7] : ms[5];

    const unsigned short* vrow = VT + (size_t)(dh*32 + l31)*NN + jt + 8*h;
    const unsigned short* hrow = HT + (size_t)(dh*32 + l31)*NN + jt + 8*h;
    short8 vb1 = *(const short8*)(vrow);
    short8 vb2 = *(const short8*)(vrow + 16);
    short8 hb1 = *(const short8*)(hrow);
    short8 hb2 = *(const short8*)(hrow + 16);

    oacc = __builtin_amdgcn_mfma_f32_32x32x16_bf16(A1.v,  vb1, oacc, 0, 0, 0);
    oacc = __builtin_amdgcn_mfma_f32_32x32x16_bf16(A2.v,  vb2, oacc, 0, 0, 0);
    oacc = __builtin_amdgcn_mfma_f32_32x32x16_bf16(Am1.v, hb1, oacc, 0, 0, 0);
    oacc = __builtin_amdgcn_mfma_f32_32x32x16_bf16(Am2.v, hb2, oacc, 0, 0, 0);

    if (t+1 < 32) {
      float* w = (t & 1) ? lw0 : lw1;
      w[0]=ra.x; w[1]=ra.y; w[2]=ra.z; w[3]=ra.w;
      w[4]=rb.x; w[5]=rb.y; w[6]=rb.z; w[7]=rb.w;
    }
    __syncthreads();
  }

  for (int r = 0; r < 16; r++) {
    int row = i0 + iq*32 + (r&3) + 8*(r>>2) + 4*h;
    int col = dh*32 + l31;
    atomicAdd(out + (size_t)row*64 + col, oacc[r]);
  }
}

// ---------------------------------------------------------------------------
extern "C" void kernel_launch(void* const* d_in, const int* in_sizes, int n_in,
                              void* d_out, int out_size, void* d_ws, size_t ws_size,
                              hipStream_t stream) {
  const float* X   = (const float*)d_in[0];
  const float* H   = (const float*)d_in[1];
  const float* M   = (const float*)d_in[2];
  const float* Qw  = (const float*)d_in[3];
  const float* Qb  = (const float*)d_in[4];
  const float* Kw  = (const float*)d_in[5];
  const float* Kb  = (const float*)d_in[6];
  const float* Vw  = (const float*)d_in[7];
  const float* Vb  = (const float*)d_in[8];
  const float* bng = (const float*)d_in[9];
  const float* bnb = (const float*)d_in[10];
  const float* bnm = (const float*)d_in[11];
  const float* bnv = (const float*)d_in[12];
  float* out = (float*)d_out;

  char* ws = (char*)d_ws;
  const size_t MB = 1024*1024;
  unsigned short* Qbf = (unsigned short*)(ws);
  unsigned short* Kbf = (unsigned short*)(ws + 1*MB);
  unsigned short* VT  = (unsigned short*)(ws + 2*MB);
  unsigned short* HT  = (unsigned short*)(ws + 3*MB);
  float* colmax   = (float*)(ws + 4*MB);
  float* colscale = (float*)(ws + 4*MB + 64*1024);
  float* pm       = (float*)(ws + 4*MB + 128*1024);
  float* pd       = (float*)(ws + 4*MB + 128*1024 + 512*1024);

  hipMemsetAsync(d_out, 0, (size_t)out_size * sizeof(float), stream);

  qkv_kernel<<<512, 256, 0, stream>>>(X, H, Qw, Qb, Kw, Kb, Vw, Vb,
                                      bng, bnb, bnm, bnv, Qbf, Kbf, VT, HT);
  pass1_kernel<<<1024, 256, 0, stream>>>(M, Qbf, Kbf, pm, pd);
  combine_kernel<<<32, 256, 0, stream>>>(pm, pd, colmax, colscale);
  pass2_kernel<<<512, 512, 0, stream>>>(M, Qbf, Kbf, VT, HT,
                                        colmax, colscale, out);
}